// Round 7
// baseline (866.863 us; speedup 1.0000x reference)
//
#include <hip/hip_runtime.h>
#include <math.h>

#define NB 16
#define NT 24
#define HP 56
#define WP 56
#define NF 32
#define ND (HP*WP*NF)   // 100352
#define NHPQ 14
#define HPITCH 36       // h_lds f-pitch (ushorts) = 72B rows -> conflict-free b128
#define UPITCH 36       // u_lds/wk_lds k-pitch = 72B (validated 2x: conflicts 5x down)
#define LN_EPS 1e-3f

typedef __attribute__((ext_vector_type(8))) short short8;
typedef __attribute__((ext_vector_type(4))) float floatx4;

// relaxed agent-scope atomics: coherent-point routed, NO buffer_inv/wbl2
// (round-2 result). NOTE round-6 errata: asm `sc1` is SYSTEM scope on gfx950
// (L2 bypass, +152MB FETCH) -- do NOT use it; these compiler atomics are the
// verified-fast agent path.
#define AT_LD(p)     __hip_atomic_load((p), __ATOMIC_RELAXED, __HIP_MEMORY_SCOPE_AGENT)
#define AT_ST(p, v)  __hip_atomic_store((p), (v), __ATOMIC_RELAXED, __HIP_MEMORY_SCOPE_AGENT)
#define AT_ADD(p, v) __hip_atomic_fetch_add((p), (v), __ATOMIC_RELAXED, __HIP_MEMORY_SCOPE_AGENT)

__device__ __forceinline__ float tanh_fast(float x){
    float e = __expf(2.0f*x);
    return 1.0f - 2.0f*__builtin_amdgcn_rcpf(e + 1.0f);
}
__device__ __forceinline__ float hsig(float z){
    return fminf(fmaxf(z*0.2f + 0.5f, 0.0f), 1.0f);
}
__device__ __forceinline__ ushort f2bf(float v){  // fp32 -> bf16 bits, RNE
    unsigned u = __float_as_uint(v);
    return (ushort)((u + 0x7fffu + ((u >> 16) & 1u)) >> 16);
}

// Persistent fused ConvLSTM+LN, v7 = v3 protocol (verified best, 430us)
//  + UPITCH 32->36 (validated: B-frag bank conflicts 1.26e7 -> 2.4e6)
//  + SHADOW-PHASE restructure: flag(t) posted immediately after B4;
//    {cnt(t-1) wait, LN bcast, out[t-1] write} moved AFTER the flag post.
//    The inter-block chain no longer contains the batch lockstep or the
//    154MB out-write issue. h(t-1) held in hout[4][4] whose live range is
//    epilogue->shadow only (never across the MFMA region -- v4 spill lesson);
//    gamma/beta re-loaded from L2 in the shadow (frees 32 persistent VGPRs).
__global__ __launch_bounds__(512, 2)
void convlstm_persist(const float* __restrict__ x,      // (B,T,112,112,3)
                      const float* __restrict__ Wk,     // (3,3,3,128)
                      const float* __restrict__ Uk,     // (3,3,32,128)
                      const float* __restrict__ bias,   // (128)
                      const float* __restrict__ gamma,  // (D)
                      const float* __restrict__ beta,   // (D)
                      ushort* __restrict__ hbuf0,       // (B,56,56,32) bf16 halo
                      ushort* __restrict__ hbuf1,
                      float* __restrict__ out,          // (B,T,D)
                      float* __restrict__ stats,        // (B*T,2)
                      int* __restrict__ cnt,            // (B*T)
                      int* __restrict__ flags)          // (T,B,14)
{
    __shared__ __attribute__((aligned(16))) ushort h_lds[6*66*HPITCH];   // 28512 B
    __shared__ __attribute__((aligned(16))) ushort x_lds[9*344];         //  6192 B
    __shared__ __attribute__((aligned(16))) ushort u_lds[9*128*UPITCH];  // 82944 B
    __shared__ __attribute__((aligned(16))) ushort wk_lds[128*UPITCH];   //  9216 B
    __shared__ float bcast[2];
    __shared__ float sred[8][2];

    const int tid  = threadIdx.x;
    const int hpq  = blockIdx.x;
    const int b    = blockIdx.y;
    const int lane = tid & 63;
    const int w    = tid >> 6;        // wave id
    const int row  = w >> 1;          // local hp row 0..3
    const int fh   = w & 1;           // f-half 0..1
    const int col  = lane & 15;
    const int q    = lane >> 4;
    const int q8   = q * 8;
    const int hp_g = hpq*4 + row;

    // ---- one-time init: zero LDS pads, convert weights to bf16 LDS ----
    for (int e = tid; e < 6*66*HPITCH; e += 512) h_lds[e] = 0;
    for (int e = tid; e < 9*344;       e += 512) x_lds[e] = 0;
    for (int e = tid; e < 9*32*128; e += 512){
        int tap = e >> 12, k = (e >> 7) & 31, n = e & 127;
        u_lds[(tap*128 + n)*UPITCH + k] = f2bf(Uk[e]);
    }
    for (int e = tid; e < 128*32; e += 512){
        int n = e >> 5, k = e & 31;
        wk_lds[n*UPITCH + k] = (k < 27) ? f2bf(Wk[k*128 + n]) : (ushort)0;
    }

    // ---- persistent registers (NO gr/br: freed, reloaded in shadow) ----
    float bg[4];
    #pragma unroll
    for (int g = 0; g < 4; g++) bg[g] = bias[g*32 + fh*16 + col];

    float creg[4][4], hreg[4][4];
    #pragma unroll
    for (int mt = 0; mt < 4; mt++)
      #pragma unroll
      for (int reg = 0; reg < 4; reg++){
          creg[mt][reg] = 0.f;
          hreg[mt][reg] = 0.f;
      }

    __syncthreads();   // init complete

    for (int t = 0; t < NT; ++t){
        // ---- stage x rows 8hpq..8hpq+8 (off the inter-block chain) ----
        {
            const float* xt = x + ((size_t)(b*NT + t))*(112*112*3);
            for (int e = tid; e < 9*84; e += 512){
                int rrow = e / 84;
                int c4   = e - rrow*84;
                int rg   = 8*hpq + rrow;
                if (rg < 112){
                    float4 v = *(const float4*)&xt[rg*336 + c4*4];
                    ushort4 s4 = {f2bf(v.x), f2bf(v.y), f2bf(v.z), f2bf(v.w)};
                    *(ushort4*)&x_lds[rrow*344 + c4*4] = s4;
                }
            }
        }
        // ---- wait neighbor halos(t-1): relaxed polls, no cache ops ----
        if (t > 0 && tid == 0){
            const int fb = ((t-1)*NB + b)*NHPQ;
            if (hpq > 0)
                while (AT_LD(&flags[fb + hpq-1]) == 0) __builtin_amdgcn_s_sleep(4);
            if (hpq < NHPQ-1)
                while (AT_LD(&flags[fb + hpq+1]) == 0) __builtin_amdgcn_s_sleep(4);
            asm volatile("" ::: "memory");
        }
        __syncthreads();                           // B1: x_lds ready, halos released

        // ---- issue halo loads (coherent 4B, compiler-tracked); commit after conv ----
        uint4 hv = {0u,0u,0u,0u};
        int hoff = -1;
        if (t > 0 && tid < 448){
            const ushort* hsrc = ((t & 1) ? hbuf0 : hbuf1) + (size_t)b*ND;
            int rsel = (tid >= 224);
            int rem  = tid - rsel*224;
            int cg   = rem >> 2, cq = rem & 3;
            int rg   = rsel ? (hpq*4 + 4) : (hpq*4 - 1);
            int ldr  = rsel ? 5 : 0;
            if (rg >= 0 && rg < HP){
                const uint* sp = (const uint*)&hsrc[((size_t)rg*WP + cg)*NF + cq*8];
                hv.x = AT_LD(sp + 0);
                hv.y = AT_LD(sp + 1);
                hv.z = AT_LD(sp + 2);
                hv.w = AT_LD(sp + 3);
                hoff = (ldr*66 + 1 + cg)*HPITCH + cq*8;
            }
        }

        // ---- accumulators with bias folded ----
        floatx4 acc[4][4];
        #pragma unroll
        for (int g = 0; g < 4; g++){
            floatx4 bv = (floatx4){bg[g], bg[g], bg[g], bg[g]};
            #pragma unroll
            for (int mt = 0; mt < 4; mt++) acc[mt][g] = bv;
        }

        // ---- input conv: one K=32 MFMA step (k>=27 zero) ----
        {
            short8 ax[4];
            #pragma unroll
            for (int mt = 0; mt < 4; mt++){
                int wp = mt*16 + col;
                short8 v;
                #pragma unroll
                for (int j = 0; j < 8; j++){
                    int k = q8 + j;
                    ushort bits = 0;
                    if (k < 27){
                        int dy = k/9; int rr = k - dy*9; int dx = rr/3; int cc = rr - dx*3;
                        int xc = 2*wp + dx; if (xc > 112) xc = 112;
                        bits = x_lds[(2*row + dy)*344 + xc*3 + cc];
                    }
                    v[j] = (short)bits;
                }
                ax[mt] = v;
            }
            #pragma unroll
            for (int g = 0; g < 4; g++){
                short8 bx = *(const short8*)&wk_lds[(g*32 + fh*16 + col)*UPITCH + q8];
                #pragma unroll
                for (int mt = 0; mt < 4; mt++)
                    acc[mt][g] = __builtin_amdgcn_mfma_f32_16x16x32_bf16(ax[mt], bx, acc[mt][g], 0, 0, 0);
            }
        }

        // ---- commit halo regs -> LDS (compiler inserts the vmcnt wait) ----
        if (hoff >= 0) *(uint4*)&h_lds[hoff] = hv;
        __syncthreads();                           // B2: h_lds (interior t-1 + halos) complete

        // ---- 9 recurrent taps, K=32 each ----
        if (t > 0){
            #pragma unroll
            for (int tap = 0; tap < 9; tap++){
                int dy = tap/3, dx = tap - dy*3;
                short8 a_[4], bb_[4];
                #pragma unroll
                for (int g = 0; g < 4; g++)
                    bb_[g] = *(const short8*)&u_lds[(tap*128 + g*32 + fh*16 + col)*UPITCH + q8];
                #pragma unroll
                for (int mt = 0; mt < 4; mt++)
                    a_[mt] = *(const short8*)&h_lds[((row + dy)*66 + mt*16 + col + dx)*HPITCH + q8];
                #pragma unroll
                for (int mt = 0; mt < 4; mt++)
                    #pragma unroll
                    for (int g = 0; g < 4; g++)
                        acc[mt][g] = __builtin_amdgcn_mfma_f32_16x16x32_bf16(a_[mt], bb_[g], acc[mt][g], 0, 0, 0);
            }
        }
        __syncthreads();                           // B3: all waves done reading h_lds/x_lds

        // ---- LSTM pointwise epilogue: save h(t-1) to hout, compute c,h(t) ----
        float hout[4][4];                          // live only epilogue -> shadow
        float lsum = 0.f, lss = 0.f;
        #pragma unroll
        for (int mt = 0; mt < 4; mt++)
          #pragma unroll
          for (int reg = 0; reg < 4; reg++){
              int wp = mt*16 + q*4 + reg;
              hout[mt][reg] = hreg[mt][reg];       // h(t-1) for the shadow write
              float zi = acc[mt][0][reg];
              float zf = acc[mt][1][reg];
              float zc = acc[mt][2][reg];
              float zo = acc[mt][3][reg];
              float ig = hsig(zi), fg = hsig(zf), og = hsig(zo);
              float cn = fg*creg[mt][reg] + ig*tanh_fast(zc);
              float hv2 = og*tanh_fast(cn);
              if (wp < WP){
                  creg[mt][reg] = cn;
                  hreg[mt][reg] = hv2;
                  h_lds[((row + 1)*66 + 1 + wp)*HPITCH + fh*16 + col] = f2bf(hv2);
                  lsum += hv2;
                  lss  += hv2*hv2;
              }
          }

        // ---- edge waves: halo rows to global (coherent 4B) + own drain ----
        if (row == 0 || row == 3){
            ushort* hdst = ((t & 1) ? hbuf1 : hbuf0) + (size_t)b*ND;
            int rg  = hpq*4 + row;
            int ldr = row ? 4 : 1;
            for (int e = lane; e < 112; e += 64){
                int cg = e >> 1, hf = e & 1;
                uint4 v = *(const uint4*)&h_lds[(ldr*66 + 1 + cg)*HPITCH + fh*16 + hf*8];
                uint* dp = (uint*)&hdst[((size_t)rg*WP + cg)*NF + fh*16 + hf*8];
                AT_ST(dp + 0, v.x);
                AT_ST(dp + 1, v.y);
                AT_ST(dp + 2, v.z);
                AT_ST(dp + 3, v.w);
            }
            // drain protocol stores so the post-B4 flag post covers them
            asm volatile("s_waitcnt vmcnt(0)" ::: "memory");
        }

        // ---- stats: wave reduce -> LDS partials ----
        #pragma unroll
        for (int off = 32; off > 0; off >>= 1){
            lsum += __shfl_down(lsum, off);
            lss  += __shfl_down(lss, off);
        }
        if (lane == 0){ sred[w][0] = lsum; sred[w][1] = lss; }

        __syncthreads();   // B4: halos drained (edge waves), sred visible

        // ---- FLAG POST FIRST: inter-block chain released here ----
        if (tid == 0){
            AT_ADD(&flags[((size_t)t*NB + b)*NHPQ + hpq], 1);
            float a0 = 0.f, a1 = 0.f;
            #pragma unroll
            for (int i = 0; i < 8; i++){ a0 += sred[i][0]; a1 += sred[i][1]; }
            AT_ADD(&stats[(size_t)(b*NT + t)*2],     a0);
            AT_ADD(&stats[(size_t)(b*NT + t)*2 + 1], a1);
            // stats adds globally visible before cnt increment
            asm volatile("s_waitcnt vmcnt(0)" ::: "memory");
            AT_ADD(&cnt[b*NT + t], 1);
        }

        // ---- shadow: LN factors for t-1 (parallel with tid0's posts) ----
        if (t > 0 && tid == 256){
            while (AT_LD(&cnt[b*NT + t-1]) < NHPQ) __builtin_amdgcn_s_sleep(4);
            asm volatile("" ::: "memory");
            float s  = AT_LD(&stats[(size_t)(b*NT + t-1)*2]);
            float ss = AT_LD(&stats[(size_t)(b*NT + t-1)*2 + 1]);
            float m  = s * (1.0f/(float)ND);
            float v  = ss * (1.0f/(float)ND) - m*m;
            bcast[0] = m;
            bcast[1] = rsqrtf(v + LN_EPS);
        }
        __syncthreads();   // B5

        // ---- shadow: normalized write of out[t-1] (off the block chain) ----
        if (t > 0){
            const float mu = bcast[0], rs = bcast[1];
            float* orow = out + ((size_t)(b*NT + t - 1))*ND;
            #pragma unroll
            for (int mt = 0; mt < 4; mt++)
              #pragma unroll
              for (int reg = 0; reg < 4; reg++){
                  int wp = mt*16 + q*4 + reg;
                  if (wp < WP){
                      size_t idx = (size_t)(hp_g*WP + wp)*NF + fh*16 + col;
                      orow[idx] = (hout[mt][reg] - mu)*rs*gamma[idx] + beta[idx];
                  }
              }
        }
    }

    // ---- final: normalized write of out[NT-1] from hreg ----
    if (tid == 256){
        while (AT_LD(&cnt[b*NT + NT-1]) < NHPQ) __builtin_amdgcn_s_sleep(4);
        asm volatile("" ::: "memory");
        float s  = AT_LD(&stats[(size_t)(b*NT + NT-1)*2]);
        float ss = AT_LD(&stats[(size_t)(b*NT + NT-1)*2 + 1]);
        float m  = s * (1.0f/(float)ND);
        float v  = ss * (1.0f/(float)ND) - m*m;
        bcast[0] = m;
        bcast[1] = rsqrtf(v + LN_EPS);
    }
    __syncthreads();
    {
        const float mu = bcast[0], rs = bcast[1];
        float* orow = out + ((size_t)(b*NT + NT - 1))*ND;
        #pragma unroll
        for (int mt = 0; mt < 4; mt++)
          #pragma unroll
          for (int reg = 0; reg < 4; reg++){
              int wp = mt*16 + q*4 + reg;
              if (wp < WP){
                  size_t idx = (size_t)(hp_g*WP + wp)*NF + fh*16 + col;
                  orow[idx] = (hreg[mt][reg] - mu)*rs*gamma[idx] + beta[idx];
              }
          }
    }
}

extern "C" void kernel_launch(void* const* d_in, const int* in_sizes, int n_in,
                              void* d_out, int out_size, void* d_ws, size_t ws_size,
                              hipStream_t stream)
{
    const float* x     = (const float*)d_in[0];
    const float* Wk    = (const float*)d_in[1];
    const float* Uk    = (const float*)d_in[2];
    const float* bias  = (const float*)d_in[3];
    const float* gamma = (const float*)d_in[4];
    const float* beta  = (const float*)d_in[5];
    float* out = (float*)d_out;

    // ws layout:
    //   hbuf0  bf16  NB*ND          (3.21 MB)
    //   hbuf1  bf16  NB*ND          (3.21 MB)
    //   stats  fp32  NB*NT*2        \
    //   cnt    int   NB*NT           } one contiguous memset
    //   flags  int   NT*NB*NHPQ    /
    char* p = (char*)d_ws;
    ushort* hbuf0 = (ushort*)p; p += (size_t)NB*ND*2;
    ushort* hbuf1 = (ushort*)p; p += (size_t)NB*ND*2;
    float*  stats = (float*)p;  p += (size_t)NB*NT*2*4;
    int*    cnt   = (int*)p;    p += (size_t)NB*NT*4;
    int*    flags = (int*)p;

    hipMemsetAsync(stats, 0, (size_t)(NB*NT*2*4 + NB*NT*4 + NT*NB*NHPQ*4), stream);
    hipLaunchKernelGGL(convlstm_persist, dim3(NHPQ, NB), dim3(512), 0, stream,
                       x, Wk, Uk, bias, gamma, beta,
                       hbuf0, hbuf1, out, stats, cnt, flags);
}

// Round 8
// 733.074 us; speedup vs baseline: 1.1825x; 1.1825x over previous
//
#include <hip/hip_runtime.h>
#include <math.h>

#define NB 16
#define NT 24
#define HP 56
#define WP 56
#define NF 32
#define ND (HP*WP*NF)   // 100352
#define NHPQ 14
#define HPITCH 36       // h_lds f-pitch (ushorts) = 72B rows -> conflict-free b128
#define UPITCH 36       // u_lds/wk_lds k-pitch = 72B rows (counter-validated 2x:
                        // B-frag conflicts 1.26e7 -> 2.4e6; measured ALONE this round)
#define LN_EPS 1e-3f

typedef __attribute__((ext_vector_type(8))) short short8;
typedef __attribute__((ext_vector_type(4))) float floatx4;

// relaxed agent-scope atomics: coherent-point routed, NO buffer_inv/wbl2
// (round-2 result). ERRATA LOG (what NOT to reintroduce):
//  r4: 2-step LN reg history -> VGPR spills, +280MB scratch FETCH
//  r5: nontemporal out-stores -> HBM-ack latency on drain, +WRITE
//  r6: asm `sc1` = SYSTEM scope on gfx950 -> L2 bypass, +152MB FETCH
//  r7: gamma/beta reload per step -> L2 evicted by out-stream, +387MB FETCH
#define AT_LD(p)     __hip_atomic_load((p), __ATOMIC_RELAXED, __HIP_MEMORY_SCOPE_AGENT)
#define AT_ST(p, v)  __hip_atomic_store((p), (v), __ATOMIC_RELAXED, __HIP_MEMORY_SCOPE_AGENT)
#define AT_ADD(p, v) __hip_atomic_fetch_add((p), (v), __ATOMIC_RELAXED, __HIP_MEMORY_SCOPE_AGENT)

__device__ __forceinline__ float tanh_fast(float x){
    float e = __expf(2.0f*x);
    return 1.0f - 2.0f*__builtin_amdgcn_rcpf(e + 1.0f);
}
__device__ __forceinline__ float hsig(float z){
    return fminf(fmaxf(z*0.2f + 0.5f, 0.0f), 1.0f);
}
__device__ __forceinline__ ushort f2bf(float v){  // fp32 -> bf16 bits, RNE
    unsigned u = __float_as_uint(v);
    return (ushort)((u + 0x7fffu + ((u >> 16) & 1u)) >> 16);
}

// Persistent fused ConvLSTM+LN, v8 = v3 VERBATIM (verified best, 430us/dispatch)
// + UPITCH 32->36 and NOTHING else. Single-variable experiment.
__global__ __launch_bounds__(512, 2)
void convlstm_persist(const float* __restrict__ x,      // (B,T,112,112,3)
                      const float* __restrict__ Wk,     // (3,3,3,128)
                      const float* __restrict__ Uk,     // (3,3,32,128)
                      const float* __restrict__ bias,   // (128)
                      const float* __restrict__ gamma,  // (D)
                      const float* __restrict__ beta,   // (D)
                      ushort* __restrict__ hbuf0,       // (B,56,56,32) bf16 halo
                      ushort* __restrict__ hbuf1,
                      float* __restrict__ out,          // (B,T,D)
                      float* __restrict__ stats,        // (B*T,2)
                      int* __restrict__ cnt,            // (B*T)
                      int* __restrict__ flags)          // (T,B,14)
{
    __shared__ __attribute__((aligned(16))) ushort h_lds[6*66*HPITCH];   // 28512 B
    __shared__ __attribute__((aligned(16))) ushort x_lds[9*344];         //  6192 B
    __shared__ __attribute__((aligned(16))) ushort u_lds[9*128*UPITCH];  // 82944 B
    __shared__ __attribute__((aligned(16))) ushort wk_lds[128*UPITCH];   //  9216 B
    __shared__ float bcast[2];
    __shared__ float sred[8][2];

    const int tid  = threadIdx.x;
    const int hpq  = blockIdx.x;
    const int b    = blockIdx.y;
    const int lane = tid & 63;
    const int w    = tid >> 6;        // wave id
    const int row  = w >> 1;          // local hp row 0..3
    const int fh   = w & 1;           // f-half 0..1
    const int col  = lane & 15;
    const int q    = lane >> 4;
    const int q8   = q * 8;
    const int hp_g = hpq*4 + row;

    // ---- one-time init: zero LDS pads, convert weights to bf16 LDS ----
    for (int e = tid; e < 6*66*HPITCH; e += 512) h_lds[e] = 0;
    for (int e = tid; e < 9*344;       e += 512) x_lds[e] = 0;
    for (int e = tid; e < 9*32*128; e += 512){
        int tap = e >> 12, k = (e >> 7) & 31, n = e & 127;
        u_lds[(tap*128 + n)*UPITCH + k] = f2bf(Uk[e]);
    }
    for (int e = tid; e < 128*32; e += 512){
        int n = e >> 5, k = e & 31;
        wk_lds[n*UPITCH + k] = (k < 27) ? f2bf(Wk[k*128 + n]) : (ushort)0;
    }

    // ---- persistent registers ----
    float bg[4];
    #pragma unroll
    for (int g = 0; g < 4; g++) bg[g] = bias[g*32 + fh*16 + col];

    float gr[4][4], br[4][4], creg[4][4], hreg[4][4];
    #pragma unroll
    for (int mt = 0; mt < 4; mt++)
      #pragma unroll
      for (int reg = 0; reg < 4; reg++){
          int wp = mt*16 + q*4 + reg;
          creg[mt][reg] = 0.f;
          hreg[mt][reg] = 0.f;
          if (wp < WP){
              size_t idx = (size_t)(hp_g*WP + wp)*NF + fh*16 + col;
              gr[mt][reg] = gamma[idx];
              br[mt][reg] = beta[idx];
          } else { gr[mt][reg] = 0.f; br[mt][reg] = 0.f; }
      }

    __syncthreads();   // init complete

    for (int t = 0; t < NT; ++t){
        // ---- stage x rows 8hpq..8hpq+8 (vectorized fp32->bf16) ----
        {
            const float* xt = x + ((size_t)(b*NT + t))*(112*112*3);
            for (int e = tid; e < 9*84; e += 512){
                int rrow = e / 84;
                int c4   = e - rrow*84;
                int rg   = 8*hpq + rrow;
                if (rg < 112){
                    float4 v = *(const float4*)&xt[rg*336 + c4*4];
                    ushort4 s4 = {f2bf(v.x), f2bf(v.y), f2bf(v.z), f2bf(v.w)};
                    *(ushort4*)&x_lds[rrow*344 + c4*4] = s4;
                }
            }
        }
        // ---- wait ONLY neighbor halos(t-1): relaxed polls, no cache ops ----
        if (t > 0 && tid == 0){
            const int fb = ((t-1)*NB + b)*NHPQ;
            if (hpq > 0)
                while (AT_LD(&flags[fb + hpq-1]) == 0) __builtin_amdgcn_s_sleep(4);
            if (hpq < NHPQ-1)
                while (AT_LD(&flags[fb + hpq+1]) == 0) __builtin_amdgcn_s_sleep(4);
            asm volatile("" ::: "memory");
        }
        __syncthreads();                           // B1: x_lds ready, halos released

        // ---- issue halo loads (coherent 4B, compiler-tracked); commit after conv ----
        uint4 hv = {0u,0u,0u,0u};
        int hoff = -1;
        if (t > 0 && tid < 448){
            const ushort* hsrc = ((t & 1) ? hbuf0 : hbuf1) + (size_t)b*ND;
            int rsel = (tid >= 224);
            int rem  = tid - rsel*224;
            int cg   = rem >> 2, cq = rem & 3;
            int rg   = rsel ? (hpq*4 + 4) : (hpq*4 - 1);
            int ldr  = rsel ? 5 : 0;
            if (rg >= 0 && rg < HP){
                const uint* sp = (const uint*)&hsrc[((size_t)rg*WP + cg)*NF + cq*8];
                hv.x = AT_LD(sp + 0);
                hv.y = AT_LD(sp + 1);
                hv.z = AT_LD(sp + 2);
                hv.w = AT_LD(sp + 3);
                hoff = (ldr*66 + 1 + cg)*HPITCH + cq*8;
            }
        }

        // ---- accumulators with bias folded ----
        floatx4 acc[4][4];
        #pragma unroll
        for (int g = 0; g < 4; g++){
            floatx4 bv = (floatx4){bg[g], bg[g], bg[g], bg[g]};
            #pragma unroll
            for (int mt = 0; mt < 4; mt++) acc[mt][g] = bv;
        }

        // ---- input conv: one K=32 MFMA step (k>=27 zero) ----
        {
            short8 ax[4];
            #pragma unroll
            for (int mt = 0; mt < 4; mt++){
                int wp = mt*16 + col;
                short8 v;
                #pragma unroll
                for (int j = 0; j < 8; j++){
                    int k = q8 + j;
                    ushort bits = 0;
                    if (k < 27){
                        int dy = k/9; int rr = k - dy*9; int dx = rr/3; int cc = rr - dx*3;
                        int xc = 2*wp + dx; if (xc > 112) xc = 112;
                        bits = x_lds[(2*row + dy)*344 + xc*3 + cc];
                    }
                    v[j] = (short)bits;
                }
                ax[mt] = v;
            }
            #pragma unroll
            for (int g = 0; g < 4; g++){
                short8 bx = *(const short8*)&wk_lds[(g*32 + fh*16 + col)*UPITCH + q8];
                #pragma unroll
                for (int mt = 0; mt < 4; mt++)
                    acc[mt][g] = __builtin_amdgcn_mfma_f32_16x16x32_bf16(ax[mt], bx, acc[mt][g], 0, 0, 0);
            }
        }

        // ---- commit halo regs -> LDS (compiler inserts the vmcnt wait) ----
        if (hoff >= 0) *(uint4*)&h_lds[hoff] = hv;
        __syncthreads();                           // B2: h_lds (interior t-1 + halos) complete

        // ---- 9 recurrent taps, K=32 each ----
        if (t > 0){
            #pragma unroll
            for (int tap = 0; tap < 9; tap++){
                int dy = tap/3, dx = tap - dy*3;
                short8 a_[4], bb_[4];
                #pragma unroll
                for (int g = 0; g < 4; g++)
                    bb_[g] = *(const short8*)&u_lds[(tap*128 + g*32 + fh*16 + col)*UPITCH + q8];
                #pragma unroll
                for (int mt = 0; mt < 4; mt++)
                    a_[mt] = *(const short8*)&h_lds[((row + dy)*66 + mt*16 + col + dx)*HPITCH + q8];
                #pragma unroll
                for (int mt = 0; mt < 4; mt++)
                    #pragma unroll
                    for (int g = 0; g < 4; g++)
                        acc[mt][g] = __builtin_amdgcn_mfma_f32_16x16x32_bf16(a_[mt], bb_[g], acc[mt][g], 0, 0, 0);
            }
        }
        __syncthreads();                           // B3: all waves done reading h_lds/x_lds

        // ---- deferred normalized write of out[t-1] (one step of slack) ----
        if (t > 0){
            if (tid == 0){
                while (AT_LD(&cnt[b*NT + t-1]) < NHPQ) __builtin_amdgcn_s_sleep(4);
                asm volatile("" ::: "memory");
                float s  = AT_LD(&stats[(size_t)(b*NT + t-1)*2]);
                float ss = AT_LD(&stats[(size_t)(b*NT + t-1)*2 + 1]);
                float m  = s * (1.0f/(float)ND);
                float v  = ss * (1.0f/(float)ND) - m*m;
                bcast[0] = m;
                bcast[1] = rsqrtf(v + LN_EPS);
            }
            __syncthreads();                       // B3b
            const float mu = bcast[0], rs = bcast[1];
            float* orow = out + ((size_t)(b*NT + t - 1))*ND;
            #pragma unroll
            for (int mt = 0; mt < 4; mt++)
              #pragma unroll
              for (int reg = 0; reg < 4; reg++){
                  int wp = mt*16 + q*4 + reg;
                  if (wp < WP)
                      orow[(size_t)(hp_g*WP + wp)*NF + fh*16 + col] =
                          (hreg[mt][reg] - mu)*rs*gr[mt][reg] + br[mt][reg];
              }
        }

        // ---- LSTM pointwise epilogue: c,h in regs, h->LDS interior ----
        float lsum = 0.f, lss = 0.f;
        #pragma unroll
        for (int mt = 0; mt < 4; mt++)
          #pragma unroll
          for (int reg = 0; reg < 4; reg++){
              int wp = mt*16 + q*4 + reg;
              float zi = acc[mt][0][reg];
              float zf = acc[mt][1][reg];
              float zc = acc[mt][2][reg];
              float zo = acc[mt][3][reg];
              float ig = hsig(zi), fg = hsig(zf), og = hsig(zo);
              float cn = fg*creg[mt][reg] + ig*tanh_fast(zc);
              float hv2 = og*tanh_fast(cn);
              if (wp < WP){
                  creg[mt][reg] = cn;
                  hreg[mt][reg] = hv2;
                  h_lds[((row + 1)*66 + 1 + wp)*HPITCH + fh*16 + col] = f2bf(hv2);
                  lsum += hv2;
                  lss  += hv2*hv2;
              }
          }

        // ---- halo rows to global: coherent 4B stores (own-row, own f-half) ----
        if (row == 0 || row == 3){
            ushort* hdst = ((t & 1) ? hbuf1 : hbuf0) + (size_t)b*ND;
            int rg  = hpq*4 + row;
            int ldr = row ? 4 : 1;
            for (int e = lane; e < 112; e += 64){
                int cg = e >> 1, hf = e & 1;
                uint4 v = *(const uint4*)&h_lds[(ldr*66 + 1 + cg)*HPITCH + fh*16 + hf*8];
                uint* dp = (uint*)&hdst[((size_t)rg*WP + cg)*NF + fh*16 + hf*8];
                AT_ST(dp + 0, v.x);
                AT_ST(dp + 1, v.y);
                AT_ST(dp + 2, v.z);
                AT_ST(dp + 3, v.w);
            }
        }

        // ---- stats: wave reduce -> LDS partials ----
        #pragma unroll
        for (int off = 32; off > 0; off >>= 1){
            lsum += __shfl_down(lsum, off);
            lss  += __shfl_down(lss, off);
        }
        if (lane == 0){ sred[w][0] = lsum; sred[w][1] = lss; }

        // drain own halo/out stores before the barrier, so tid0's flag post
        // after B4 is ordered behind ALL waves' coherent stores
        asm volatile("s_waitcnt vmcnt(0)" ::: "memory");
        __syncthreads();   // B4
        if (tid == 0){
            float a0 = 0.f, a1 = 0.f;
            #pragma unroll
            for (int i = 0; i < 8; i++){ a0 += sred[i][0]; a1 += sred[i][1]; }
            AT_ADD(&stats[(size_t)(b*NT + t)*2],     a0);
            AT_ADD(&stats[(size_t)(b*NT + t)*2 + 1], a1);
            // stats adds must be globally visible before cnt/flags increments
            asm volatile("s_waitcnt vmcnt(0)" ::: "memory");
            AT_ADD(&cnt[b*NT + t], 1);
            AT_ADD(&flags[((size_t)t*NB + b)*NHPQ + hpq], 1);
        }
    }

    // ---- final: normalized write of out[NT-1] ----
    if (tid == 0){
        while (AT_LD(&cnt[b*NT + NT-1]) < NHPQ) __builtin_amdgcn_s_sleep(4);
        asm volatile("" ::: "memory");
        float s  = AT_LD(&stats[(size_t)(b*NT + NT-1)*2]);
        float ss = AT_LD(&stats[(size_t)(b*NT + NT-1)*2 + 1]);
        float m  = s * (1.0f/(float)ND);
        float v  = ss * (1.0f/(float)ND) - m*m;
        bcast[0] = m;
        bcast[1] = rsqrtf(v + LN_EPS);
    }
    __syncthreads();
    {
        const float mu = bcast[0], rs = bcast[1];
        float* orow = out + ((size_t)(b*NT + NT - 1))*ND;
        #pragma unroll
        for (int mt = 0; mt < 4; mt++)
          #pragma unroll
          for (int reg = 0; reg < 4; reg++){
              int wp = mt*16 + q*4 + reg;
              if (wp < WP)
                  orow[(size_t)(hp_g*WP + wp)*NF + fh*16 + col] =
                      (hreg[mt][reg] - mu)*rs*gr[mt][reg] + br[mt][reg];
          }
    }
}

extern "C" void kernel_launch(void* const* d_in, const int* in_sizes, int n_in,
                              void* d_out, int out_size, void* d_ws, size_t ws_size,
                              hipStream_t stream)
{
    const float* x     = (const float*)d_in[0];
    const float* Wk    = (const float*)d_in[1];
    const float* Uk    = (const float*)d_in[2];
    const float* bias  = (const float*)d_in[3];
    const float* gamma = (const float*)d_in[4];
    const float* beta  = (const float*)d_in[5];
    float* out = (float*)d_out;

    // ws layout:
    //   hbuf0  bf16  NB*ND          (3.21 MB)
    //   hbuf1  bf16  NB*ND          (3.21 MB)
    //   stats  fp32  NB*NT*2        \
    //   cnt    int   NB*NT           } one contiguous memset
    //   flags  int   NT*NB*NHPQ    /
    char* p = (char*)d_ws;
    ushort* hbuf0 = (ushort*)p; p += (size_t)NB*ND*2;
    ushort* hbuf1 = (ushort*)p; p += (size_t)NB*ND*2;
    float*  stats = (float*)p;  p += (size_t)NB*NT*2*4;
    int*    cnt   = (int*)p;    p += (size_t)NB*NT*4;
    int*    flags = (int*)p;

    hipMemsetAsync(stats, 0, (size_t)(NB*NT*2*4 + NB*NT*4 + NT*NB*NHPQ*4), stream);
    hipLaunchKernelGGL(convlstm_persist, dim3(NHPQ, NB), dim3(512), 0, stream,
                       x, Wk, Uk, bias, gamma, beta,
                       hbuf0, hbuf1, out, stats, cnt, flags);
}

// Round 9
// 546.826 us; speedup vs baseline: 1.5853x; 1.3406x over previous
//
#include <hip/hip_runtime.h>
#include <math.h>

#define NB 16
#define NT 24
#define HP 56
#define WP 56
#define NF 32
#define ND (HP*WP*NF)   // 100352
#define NHPQ 14
#define HPITCH 36       // h_lds f-pitch (ushorts) = 72B rows (v3 value)
#define LN_EPS 1e-3f

typedef __attribute__((ext_vector_type(8))) short short8;
typedef __attribute__((ext_vector_type(4))) float floatx4;
typedef unsigned long long u64;

// relaxed agent-scope atomics: coherent-point routed, NO buffer_inv/wbl2
// (round-2 result). ERRATA LOG (do NOT reintroduce):
//  r4: 2-step LN reg history -> VGPR spills, +280MB scratch FETCH
//  r5: nontemporal out-stores -> HBM-ack latency on drain path
//  r6: asm `sc1` = SYSTEM scope on gfx950 -> L2 bypass, +152MB FETCH
//  r7: gamma/beta reload per step -> L2 evicted by out-stream, +387MB FETCH
//  r8: UPITCH=36 alone -> +123MB FETCH (out write-allocate side effect), dur +38%
// Traffic model (r8): dur ~= hbm_bytes / 0.95 TB/s -> optimize BYTES.
#define AT_LD(p)     __hip_atomic_load((p), __ATOMIC_RELAXED, __HIP_MEMORY_SCOPE_AGENT)
#define AT_ST(p, v)  __hip_atomic_store((p), (v), __ATOMIC_RELAXED, __HIP_MEMORY_SCOPE_AGENT)
#define AT_ADD(p, v) __hip_atomic_fetch_add((p), (v), __ATOMIC_RELAXED, __HIP_MEMORY_SCOPE_AGENT)

__device__ __forceinline__ float tanh_fast(float x){
    float e = __expf(2.0f*x);
    return 1.0f - 2.0f*__builtin_amdgcn_rcpf(e + 1.0f);
}
__device__ __forceinline__ float hsig(float z){
    return fminf(fmaxf(z*0.2f + 0.5f, 0.0f), 1.0f);
}
__device__ __forceinline__ ushort f2bf(float v){  // fp32 -> bf16 bits, RNE
    unsigned u = __float_as_uint(v);
    return (ushort)((u + 0x7fffu + ((u >> 16) & 1u)) >> 16);
}

// Persistent fused ConvLSTM+LN, v9 = v3 VERBATIM (best: 430us, 412MB) with:
//  (a) halo transfers as 2x8B relaxed-agent atomics instead of 4x4B
//      (halves op count -> halves the ~165MB per-op burst amplification)
//  (b) grid transposed to (NB, NHPQ): linear wg = b + 16*hpq, so same-batch
//      hpq-neighbors are 16 apart = 0 mod 8 XCDs -> whole batch pipeline
//      co-located on one XCD under round-robin dispatch (halo + stats
//      atomics XCD-local). Pure remap; co-residency unchanged (224 blocks).
__global__ __launch_bounds__(512, 2)
void convlstm_persist(const float* __restrict__ x,      // (B,T,112,112,3)
                      const float* __restrict__ Wk,     // (3,3,3,128)
                      const float* __restrict__ Uk,     // (3,3,32,128)
                      const float* __restrict__ bias,   // (128)
                      const float* __restrict__ gamma,  // (D)
                      const float* __restrict__ beta,   // (D)
                      ushort* __restrict__ hbuf0,       // (B,56,56,32) bf16 halo
                      ushort* __restrict__ hbuf1,
                      float* __restrict__ out,          // (B,T,D)
                      float* __restrict__ stats,        // (B*T,2)
                      int* __restrict__ cnt,            // (B*T)
                      int* __restrict__ flags)          // (T,B,14)
{
    __shared__ __attribute__((aligned(16))) ushort h_lds[6*66*HPITCH];   // 28512 B
    __shared__ __attribute__((aligned(16))) ushort x_lds[9*344];         //  6192 B
    __shared__ __attribute__((aligned(16))) ushort u_lds[9*128*32];      // 73728 B
    __shared__ __attribute__((aligned(16))) ushort wk_lds[128*32];       //  8192 B
    __shared__ float bcast[2];
    __shared__ float sred[8][2];

    const int tid  = threadIdx.x;
    const int b    = blockIdx.x;      // (b) grid transpose: batch-major linear id
    const int hpq  = blockIdx.y;      //     -> same-batch neighbors on same XCD
    const int lane = tid & 63;
    const int w    = tid >> 6;        // wave id
    const int row  = w >> 1;          // local hp row 0..3
    const int fh   = w & 1;           // f-half 0..1
    const int col  = lane & 15;
    const int q    = lane >> 4;
    const int q8   = q * 8;
    const int hp_g = hpq*4 + row;

    // ---- one-time init: zero LDS pads, convert weights to bf16 LDS ----
    for (int e = tid; e < 6*66*HPITCH; e += 512) h_lds[e] = 0;
    for (int e = tid; e < 9*344;       e += 512) x_lds[e] = 0;
    for (int e = tid; e < 9*32*128; e += 512){
        int tap = e >> 12, k = (e >> 7) & 31, n = e & 127;
        u_lds[(tap*128 + n)*32 + k] = f2bf(Uk[e]);
    }
    for (int e = tid; e < 128*32; e += 512){
        int n = e >> 5, k = e & 31;
        wk_lds[n*32 + k] = (k < 27) ? f2bf(Wk[k*128 + n]) : (ushort)0;
    }

    // ---- persistent registers ----
    float bg[4];
    #pragma unroll
    for (int g = 0; g < 4; g++) bg[g] = bias[g*32 + fh*16 + col];

    float gr[4][4], br[4][4], creg[4][4], hreg[4][4];
    #pragma unroll
    for (int mt = 0; mt < 4; mt++)
      #pragma unroll
      for (int reg = 0; reg < 4; reg++){
          int wp = mt*16 + q*4 + reg;
          creg[mt][reg] = 0.f;
          hreg[mt][reg] = 0.f;
          if (wp < WP){
              size_t idx = (size_t)(hp_g*WP + wp)*NF + fh*16 + col;
              gr[mt][reg] = gamma[idx];
              br[mt][reg] = beta[idx];
          } else { gr[mt][reg] = 0.f; br[mt][reg] = 0.f; }
      }

    __syncthreads();   // init complete

    for (int t = 0; t < NT; ++t){
        // ---- stage x rows 8hpq..8hpq+8 (vectorized fp32->bf16) ----
        {
            const float* xt = x + ((size_t)(b*NT + t))*(112*112*3);
            for (int e = tid; e < 9*84; e += 512){
                int rrow = e / 84;
                int c4   = e - rrow*84;
                int rg   = 8*hpq + rrow;
                if (rg < 112){
                    float4 v = *(const float4*)&xt[rg*336 + c4*4];
                    ushort4 s4 = {f2bf(v.x), f2bf(v.y), f2bf(v.z), f2bf(v.w)};
                    *(ushort4*)&x_lds[rrow*344 + c4*4] = s4;
                }
            }
        }
        // ---- wait ONLY neighbor halos(t-1): relaxed polls, no cache ops ----
        if (t > 0 && tid == 0){
            const int fb = ((t-1)*NB + b)*NHPQ;
            if (hpq > 0)
                while (AT_LD(&flags[fb + hpq-1]) == 0) __builtin_amdgcn_s_sleep(4);
            if (hpq < NHPQ-1)
                while (AT_LD(&flags[fb + hpq+1]) == 0) __builtin_amdgcn_s_sleep(4);
            asm volatile("" ::: "memory");
        }
        __syncthreads();                           // B1: x_lds ready, halos released

        // ---- issue halo loads (coherent 2x8B, compiler-tracked); commit after conv ----
        u64 h0 = 0ull, h1 = 0ull;
        int hoff = -1;
        if (t > 0 && tid < 448){
            const ushort* hsrc = ((t & 1) ? hbuf0 : hbuf1) + (size_t)b*ND;
            int rsel = (tid >= 224);
            int rem  = tid - rsel*224;
            int cg   = rem >> 2, cq = rem & 3;
            int rg   = rsel ? (hpq*4 + 4) : (hpq*4 - 1);
            int ldr  = rsel ? 5 : 0;
            if (rg >= 0 && rg < HP){
                const u64* sp = (const u64*)&hsrc[((size_t)rg*WP + cg)*NF + cq*8];
                h0 = AT_LD(sp + 0);
                h1 = AT_LD(sp + 1);
                hoff = (ldr*66 + 1 + cg)*HPITCH + cq*8;
            }
        }

        // ---- accumulators with bias folded ----
        floatx4 acc[4][4];
        #pragma unroll
        for (int g = 0; g < 4; g++){
            floatx4 bv = (floatx4){bg[g], bg[g], bg[g], bg[g]};
            #pragma unroll
            for (int mt = 0; mt < 4; mt++) acc[mt][g] = bv;
        }

        // ---- input conv: one K=32 MFMA step (k>=27 zero) ----
        {
            short8 ax[4];
            #pragma unroll
            for (int mt = 0; mt < 4; mt++){
                int wp = mt*16 + col;
                short8 v;
                #pragma unroll
                for (int j = 0; j < 8; j++){
                    int k = q8 + j;
                    ushort bits = 0;
                    if (k < 27){
                        int dy = k/9; int rr = k - dy*9; int dx = rr/3; int cc = rr - dx*3;
                        int xc = 2*wp + dx; if (xc > 112) xc = 112;
                        bits = x_lds[(2*row + dy)*344 + xc*3 + cc];
                    }
                    v[j] = (short)bits;
                }
                ax[mt] = v;
            }
            #pragma unroll
            for (int g = 0; g < 4; g++){
                short8 bx = *(const short8*)&wk_lds[(g*32 + fh*16 + col)*32 + q8];
                #pragma unroll
                for (int mt = 0; mt < 4; mt++)
                    acc[mt][g] = __builtin_amdgcn_mfma_f32_16x16x32_bf16(ax[mt], bx, acc[mt][g], 0, 0, 0);
            }
        }

        // ---- commit halo regs -> LDS (compiler inserts the vmcnt wait) ----
        if (hoff >= 0){
            *(u64*)&h_lds[hoff]     = h0;   // 8B-aligned (72B row pitch)
            *(u64*)&h_lds[hoff + 4] = h1;
        }
        __syncthreads();                           // B2: h_lds (interior t-1 + halos) complete

        // ---- 9 recurrent taps, K=32 each ----
        if (t > 0){
            #pragma unroll
            for (int tap = 0; tap < 9; tap++){
                int dy = tap/3, dx = tap - dy*3;
                short8 a_[4], bb_[4];
                #pragma unroll
                for (int g = 0; g < 4; g++)
                    bb_[g] = *(const short8*)&u_lds[(tap*128 + g*32 + fh*16 + col)*32 + q8];
                #pragma unroll
                for (int mt = 0; mt < 4; mt++)
                    a_[mt] = *(const short8*)&h_lds[((row + dy)*66 + mt*16 + col + dx)*HPITCH + q8];
                #pragma unroll
                for (int mt = 0; mt < 4; mt++)
                    #pragma unroll
                    for (int g = 0; g < 4; g++)
                        acc[mt][g] = __builtin_amdgcn_mfma_f32_16x16x32_bf16(a_[mt], bb_[g], acc[mt][g], 0, 0, 0);
            }
        }
        __syncthreads();                           // B3: all waves done reading h_lds/x_lds

        // ---- deferred normalized write of out[t-1] (one step of slack) ----
        if (t > 0){
            if (tid == 0){
                while (AT_LD(&cnt[b*NT + t-1]) < NHPQ) __builtin_amdgcn_s_sleep(4);
                asm volatile("" ::: "memory");
                float s  = AT_LD(&stats[(size_t)(b*NT + t-1)*2]);
                float ss = AT_LD(&stats[(size_t)(b*NT + t-1)*2 + 1]);
                float m  = s * (1.0f/(float)ND);
                float v  = ss * (1.0f/(float)ND) - m*m;
                bcast[0] = m;
                bcast[1] = rsqrtf(v + LN_EPS);
            }
            __syncthreads();                       // B3b
            const float mu = bcast[0], rs = bcast[1];
            float* orow = out + ((size_t)(b*NT + t - 1))*ND;
            #pragma unroll
            for (int mt = 0; mt < 4; mt++)
              #pragma unroll
              for (int reg = 0; reg < 4; reg++){
                  int wp = mt*16 + q*4 + reg;
                  if (wp < WP)
                      orow[(size_t)(hp_g*WP + wp)*NF + fh*16 + col] =
                          (hreg[mt][reg] - mu)*rs*gr[mt][reg] + br[mt][reg];
              }
        }

        // ---- LSTM pointwise epilogue: c,h in regs, h->LDS interior ----
        float lsum = 0.f, lss = 0.f;
        #pragma unroll
        for (int mt = 0; mt < 4; mt++)
          #pragma unroll
          for (int reg = 0; reg < 4; reg++){
              int wp = mt*16 + q*4 + reg;
              float zi = acc[mt][0][reg];
              float zf = acc[mt][1][reg];
              float zc = acc[mt][2][reg];
              float zo = acc[mt][3][reg];
              float ig = hsig(zi), fg = hsig(zf), og = hsig(zo);
              float cn = fg*creg[mt][reg] + ig*tanh_fast(zc);
              float hv2 = og*tanh_fast(cn);
              if (wp < WP){
                  creg[mt][reg] = cn;
                  hreg[mt][reg] = hv2;
                  h_lds[((row + 1)*66 + 1 + wp)*HPITCH + fh*16 + col] = f2bf(hv2);
                  lsum += hv2;
                  lss  += hv2*hv2;
              }
          }

        // ---- halo rows to global: coherent 2x8B stores (own-row, own f-half) ----
        if (row == 0 || row == 3){
            ushort* hdst = ((t & 1) ? hbuf1 : hbuf0) + (size_t)b*ND;
            int rg  = hpq*4 + row;
            int ldr = row ? 4 : 1;
            for (int e = lane; e < 112; e += 64){
                int cg = e >> 1, hf = e & 1;
                const u64* sv = (const u64*)&h_lds[(ldr*66 + 1 + cg)*HPITCH + fh*16 + hf*8];
                u64* dp = (u64*)&hdst[((size_t)rg*WP + cg)*NF + fh*16 + hf*8];
                AT_ST(dp + 0, sv[0]);
                AT_ST(dp + 1, sv[1]);
            }
        }

        // ---- stats: wave reduce -> LDS partials ----
        #pragma unroll
        for (int off = 32; off > 0; off >>= 1){
            lsum += __shfl_down(lsum, off);
            lss  += __shfl_down(lss, off);
        }
        if (lane == 0){ sred[w][0] = lsum; sred[w][1] = lss; }

        // drain own halo/out stores before the barrier, so tid0's flag post
        // after B4 is ordered behind ALL waves' coherent stores
        asm volatile("s_waitcnt vmcnt(0)" ::: "memory");
        __syncthreads();   // B4
        if (tid == 0){
            float a0 = 0.f, a1 = 0.f;
            #pragma unroll
            for (int i = 0; i < 8; i++){ a0 += sred[i][0]; a1 += sred[i][1]; }
            AT_ADD(&stats[(size_t)(b*NT + t)*2],     a0);
            AT_ADD(&stats[(size_t)(b*NT + t)*2 + 1], a1);
            // stats adds must be globally visible before cnt/flags increments
            asm volatile("s_waitcnt vmcnt(0)" ::: "memory");
            AT_ADD(&cnt[b*NT + t], 1);
            AT_ADD(&flags[((size_t)t*NB + b)*NHPQ + hpq], 1);
        }
    }

    // ---- final: normalized write of out[NT-1] ----
    if (tid == 0){
        while (AT_LD(&cnt[b*NT + NT-1]) < NHPQ) __builtin_amdgcn_s_sleep(4);
        asm volatile("" ::: "memory");
        float s  = AT_LD(&stats[(size_t)(b*NT + NT-1)*2]);
        float ss = AT_LD(&stats[(size_t)(b*NT + NT-1)*2 + 1]);
        float m  = s * (1.0f/(float)ND);
        float v  = ss * (1.0f/(float)ND) - m*m;
        bcast[0] = m;
        bcast[1] = rsqrtf(v + LN_EPS);
    }
    __syncthreads();
    {
        const float mu = bcast[0], rs = bcast[1];
        float* orow = out + ((size_t)(b*NT + NT - 1))*ND;
        #pragma unroll
        for (int mt = 0; mt < 4; mt++)
          #pragma unroll
          for (int reg = 0; reg < 4; reg++){
              int wp = mt*16 + q*4 + reg;
              if (wp < WP)
                  orow[(size_t)(hp_g*WP + wp)*NF + fh*16 + col] =
                      (hreg[mt][reg] - mu)*rs*gr[mt][reg] + br[mt][reg];
          }
    }
}

extern "C" void kernel_launch(void* const* d_in, const int* in_sizes, int n_in,
                              void* d_out, int out_size, void* d_ws, size_t ws_size,
                              hipStream_t stream)
{
    const float* x     = (const float*)d_in[0];
    const float* Wk    = (const float*)d_in[1];
    const float* Uk    = (const float*)d_in[2];
    const float* bias  = (const float*)d_in[3];
    const float* gamma = (const float*)d_in[4];
    const float* beta  = (const float*)d_in[5];
    float* out = (float*)d_out;

    // ws layout:
    //   hbuf0  bf16  NB*ND          (3.21 MB)
    //   hbuf1  bf16  NB*ND          (3.21 MB)
    //   stats  fp32  NB*NT*2        \
    //   cnt    int   NB*NT           } one contiguous memset
    //   flags  int   NT*NB*NHPQ    /
    char* p = (char*)d_ws;
    ushort* hbuf0 = (ushort*)p; p += (size_t)NB*ND*2;
    ushort* hbuf1 = (ushort*)p; p += (size_t)NB*ND*2;
    float*  stats = (float*)p;  p += (size_t)NB*NT*2*4;
    int*    cnt   = (int*)p;    p += (size_t)NB*NT*4;
    int*    flags = (int*)p;

    hipMemsetAsync(stats, 0, (size_t)(NB*NT*2*4 + NB*NT*4 + NT*NB*NHPQ*4), stream);
    // grid transposed: blockIdx.x = b (16), blockIdx.y = hpq (14)
    // -> linear wg = b + 16*hpq; same-batch hpq-neighbors 16 apart = same XCD
    hipLaunchKernelGGL(convlstm_persist, dim3(NB, NHPQ), dim3(512), 0, stream,
                       x, Wk, Uk, bias, gamma, beta,
                       hbuf0, hbuf1, out, stats, cnt, flags);
}